// Round 2
// baseline (376.480 us; speedup 1.0000x reference)
//
#include <hip/hip_runtime.h>
#include <hip/hip_bf16.h>

typedef __attribute__((ext_vector_type(8))) short bf16x8;
typedef __attribute__((ext_vector_type(4))) float f32x4;

__device__ __forceinline__ unsigned short f2bf(float f) {
    union { float f; unsigned int u; } v; v.f = f;
    unsigned int u = v.u;
    u += 0x7fffu + ((u >> 16) & 1u);   // round-to-nearest-even
    return (unsigned short)(u >> 16);
}

// ---------------------------------------------------------------------------
// GEMM: C[m][n] = sum_k A[m][k] * W[n][k] + bias[n]
// M=8192, N=512, K=512. 128x128 tile, BK=32, 256 threads (4 waves, 2x2),
// each wave computes 64x64 = 4x4 frags of 16x16x32 bf16 MFMA.
// OUT_MODE: 0 = fp32 row-major [M][N] (final output)
//           1 = bf16 per-head [b*8+h][s][64]        (Q, K)
//           2 = bf16 per-head transposed [b*8+h][64][s]  (V^T)
// A_BF16: 0 = A is fp32 (cast in staging), 1 = A is bf16 row-major
// ---------------------------------------------------------------------------
template<int OUT_MODE, int A_BF16>
__global__ __launch_bounds__(256, 2)
void gemm512(const void* __restrict__ Ap, const float* __restrict__ W,
             const float* __restrict__ bias, void* __restrict__ Outp)
{
    constexpr int Kdim = 512;
    __shared__ unsigned short As[128][40];   // +8 pad: 80B row stride
    __shared__ unsigned short Bs[128][40];

    const int t = threadIdx.x;
    const int w = t >> 6, lane = t & 63, g = lane >> 4, c = lane & 15;
    const int wr = w >> 1, wc = w & 1;
    const int bm = blockIdx.x * 128, bn = blockIdx.y * 128;

    f32x4 acc[4][4] = {};

    for (int k0 = 0; k0 < Kdim; k0 += 32) {
        __syncthreads();
        // ---- stage A tile [128][32] ----
        if (A_BF16) {
            const unsigned short* A = (const unsigned short*)Ap;
            int cc = (t & 3) * 8, r0 = t >> 2;
            for (int p = 0; p < 2; ++p) {
                int r = r0 + p * 64;
                uint4 v = *(const uint4*)(A + (size_t)(bm + r) * Kdim + k0 + cc);
                *(uint4*)&As[r][cc] = v;
            }
        } else {
            const float* A = (const float*)Ap;
            int c4 = (t & 7) * 4, r0 = t >> 3;
            for (int p = 0; p < 4; ++p) {
                int r = r0 + p * 32;
                float4 v = *(const float4*)(A + (size_t)(bm + r) * Kdim + k0 + c4);
                ushort4 hv;
                hv.x = f2bf(v.x); hv.y = f2bf(v.y); hv.z = f2bf(v.z); hv.w = f2bf(v.w);
                *(ushort4*)&As[r][c4] = hv;
            }
        }
        // ---- stage B tile [128][32] from W (always fp32) ----
        {
            int c4 = (t & 7) * 4, r0 = t >> 3;
            for (int p = 0; p < 4; ++p) {
                int r = r0 + p * 32;
                float4 v = *(const float4*)(W + (size_t)(bn + r) * Kdim + k0 + c4);
                ushort4 hv;
                hv.x = f2bf(v.x); hv.y = f2bf(v.y); hv.z = f2bf(v.z); hv.w = f2bf(v.w);
                *(ushort4*)&Bs[r][c4] = hv;
            }
        }
        __syncthreads();
        // ---- fragments + MFMA ----
        bf16x8 af[4], bfr[4];
        for (int i = 0; i < 4; ++i)
            af[i] = *(const bf16x8*)&As[wr * 64 + i * 16 + c][g * 8];
        for (int j = 0; j < 4; ++j)
            bfr[j] = *(const bf16x8*)&Bs[wc * 64 + j * 16 + c][g * 8];
        for (int i = 0; i < 4; ++i)
            for (int j = 0; j < 4; ++j)
                acc[i][j] = __builtin_amdgcn_mfma_f32_16x16x32_bf16(af[i], bfr[j], acc[i][j], 0, 0, 0);
    }

    // ---- epilogue ----
    float bv[4];
    for (int j = 0; j < 4; ++j) bv[j] = bias[bn + wc * 64 + j * 16 + c];
    for (int i = 0; i < 4; ++i)
        for (int j = 0; j < 4; ++j)
            for (int r = 0; r < 4; ++r) {
                int m = bm + wr * 64 + i * 16 + 4 * g + r;
                int n = bn + wc * 64 + j * 16 + c;
                float val = acc[i][j][r] + bv[j];
                if (OUT_MODE == 0) {
                    ((float*)Outp)[(size_t)m * 512 + n] = val;
                } else if (OUT_MODE == 1) {
                    int b = m >> 12, s = m & 4095, h = n >> 6, d = n & 63;
                    ((unsigned short*)Outp)[((((size_t)b * 8 + h) * 4096 + s) << 6) + d] = f2bf(val);
                } else {
                    int b = m >> 12, s = m & 4095, h = n >> 6, d = n & 63;
                    ((unsigned short*)Outp)[(((size_t)b * 8 + h) * 64 + d) * 4096 + s] = f2bf(val);
                }
            }
}

// ---------------------------------------------------------------------------
// Flash attention fwd. Q,K: [16][4096][64] bf16; VT: [16][64][4096] bf16.
// Block = 4 waves, 64 Q-rows (16 per wave); KV-tile = 64. Output: merged
// bf16 [8192][512].
// ---------------------------------------------------------------------------
__global__ __launch_bounds__(256, 2)
void attn64(const unsigned short* __restrict__ Q, const unsigned short* __restrict__ Kh,
            const unsigned short* __restrict__ VT, unsigned short* __restrict__ Mo)
{
    __shared__ unsigned short Ks[64][72];   // [key][dh], 144B row stride
    __shared__ unsigned short Vs[64][72];   // [dh][key]
    __shared__ unsigned short Ps[64][72];   // [qrow][key] per-wave slices

    const int t = threadIdx.x, w = t >> 6, lane = t & 63, g = lane >> 4, c = lane & 15;
    const int bh = blockIdx.y;
    const int q0 = blockIdx.x * 64;
    const unsigned short* Qb = Q + (size_t)bh * 4096 * 64;
    const unsigned short* Kb = Kh + (size_t)bh * 4096 * 64;
    const unsigned short* Vb = VT + (size_t)bh * 64 * 4096;

    // Q fragments hoisted (16 rows per wave)
    bf16x8 qf[2];
    {
        int qr = q0 + w * 16 + c;
        qf[0] = *(const bf16x8*)(Qb + (size_t)qr * 64 + g * 8);
        qf[1] = *(const bf16x8*)(Qb + (size_t)qr * 64 + 32 + g * 8);
    }

    f32x4 o[4] = {};
    float mrun[4], lrun[4];
    for (int r = 0; r < 4; ++r) { mrun[r] = -1e30f; lrun[r] = 0.f; }

    // staging: 64 rows x 64 shorts (128B) per buffer -> 2 x uint4 per thread
    const int srow = t >> 2, scol = (t & 3) * 16;

    for (int j0 = 0; j0 < 4096; j0 += 64) {
        __syncthreads();
        // stage K [64 keys][64 dh] and V^T [64 dh][64 keys] -- FULL rows
        {
            const unsigned short* kp = Kb + (size_t)(j0 + srow) * 64 + scol;
            uint4 k0v = *(const uint4*)(kp);
            uint4 k1v = *(const uint4*)(kp + 8);
            *(uint4*)&Ks[srow][scol]     = k0v;
            *(uint4*)&Ks[srow][scol + 8] = k1v;
            const unsigned short* vp = Vb + (size_t)srow * 4096 + j0 + scol;
            uint4 v0v = *(const uint4*)(vp);
            uint4 v1v = *(const uint4*)(vp + 8);
            *(uint4*)&Vs[srow][scol]     = v0v;
            *(uint4*)&Vs[srow][scol + 8] = v1v;
        }
        __syncthreads();

        // S = (Q K^T): 16 q-rows x 64 keys per wave
        f32x4 s[4];
        for (int nt = 0; nt < 4; ++nt) {
            bf16x8 kf0 = *(const bf16x8*)&Ks[nt * 16 + c][g * 8];
            bf16x8 kf1 = *(const bf16x8*)&Ks[nt * 16 + c][32 + g * 8];
            f32x4 z = {};
            z = __builtin_amdgcn_mfma_f32_16x16x32_bf16(qf[0], kf0, z, 0, 0, 0);
            z = __builtin_amdgcn_mfma_f32_16x16x32_bf16(qf[1], kf1, z, 0, 0, 0);
            s[nt] = z;
        }

        // online softmax (rows live across 16-lane groups; 4 rows/lane in regs)
        const float sc = 0.125f;
        float tmax[4], psum[4], alpha[4];
        for (int r = 0; r < 4; ++r)
            tmax[r] = fmaxf(fmaxf(s[0][r], s[1][r]), fmaxf(s[2][r], s[3][r]));
        for (int mk = 1; mk < 16; mk <<= 1)
            for (int r = 0; r < 4; ++r)
                tmax[r] = fmaxf(tmax[r], __shfl_xor(tmax[r], mk));
        for (int r = 0; r < 4; ++r) {
            float mn = fmaxf(mrun[r], tmax[r] * sc);
            alpha[r] = __expf(mrun[r] - mn);
            mrun[r] = mn;
            psum[r] = 0.f;
        }
        for (int nt = 0; nt < 4; ++nt)
            for (int r = 0; r < 4; ++r) {
                float p = __expf(s[nt][r] * sc - mrun[r]);
                s[nt][r] = p;
                psum[r] += p;
            }
        for (int mk = 1; mk < 16; mk <<= 1)
            for (int r = 0; r < 4; ++r)
                psum[r] += __shfl_xor(psum[r], mk);
        for (int r = 0; r < 4; ++r)
            lrun[r] = lrun[r] * alpha[r] + psum[r];
        for (int nt = 0; nt < 4; ++nt)
            for (int r = 0; r < 4; ++r)
                o[nt][r] *= alpha[r];

        // P -> LDS (D-layout) -> A-fragment layout (same-wave, no barrier)
        for (int nt = 0; nt < 4; ++nt)
            for (int r = 0; r < 4; ++r)
                Ps[w * 16 + 4 * g + r][nt * 16 + c] = f2bf(s[nt][r]);
        bf16x8 pf0 = *(const bf16x8*)&Ps[w * 16 + c][g * 8];
        bf16x8 pf1 = *(const bf16x8*)&Ps[w * 16 + c][32 + g * 8];

        // O += P V
        for (int nt = 0; nt < 4; ++nt) {
            bf16x8 v0 = *(const bf16x8*)&Vs[nt * 16 + c][g * 8];
            bf16x8 v1 = *(const bf16x8*)&Vs[nt * 16 + c][32 + g * 8];
            o[nt] = __builtin_amdgcn_mfma_f32_16x16x32_bf16(pf0, v0, o[nt], 0, 0, 0);
            o[nt] = __builtin_amdgcn_mfma_f32_16x16x32_bf16(pf1, v1, o[nt], 0, 0, 0);
        }
    }

    // epilogue: O / l -> merged [8192][512] bf16
    const int b = bh >> 3, h = bh & 7;
    for (int r = 0; r < 4; ++r) {
        float inv = 1.f / lrun[r];
        int m = b * 4096 + q0 + w * 16 + 4 * g + r;
        for (int nt = 0; nt < 4; ++nt) {
            int n = h * 64 + nt * 16 + c;
            Mo[(size_t)m * 512 + n] = f2bf(o[nt][r] * inv);
        }
    }
}

extern "C" void kernel_launch(void* const* d_in, const int* in_sizes, int n_in,
                              void* d_out, int out_size, void* d_ws, size_t ws_size,
                              hipStream_t stream) {
    const float* q  = (const float*)d_in[0];
    const float* Wq = (const float*)d_in[1];
    const float* bq = (const float*)d_in[2];
    const float* Wk = (const float*)d_in[3];
    const float* bk = (const float*)d_in[4];
    const float* Wv = (const float*)d_in[5];
    const float* bv = (const float*)d_in[6];
    const float* Wo = (const float*)d_in[7];
    const float* bo = (const float*)d_in[8];

    unsigned short* Qb = (unsigned short*)d_ws;            // 16*4096*64 bf16 = 8 MB
    unsigned short* Kb = Qb + (size_t)16 * 4096 * 64;      // 8 MB
    unsigned short* Vt = Kb + (size_t)16 * 4096 * 64;      // 8 MB (transposed per head)
    unsigned short* Mg = Vt + (size_t)16 * 4096 * 64;      // merged bf16 [8192][512], 8 MB

    dim3 gg(64, 4), gb(256);
    gemm512<1, 0><<<gg, gb, 0, stream>>>((const void*)q, Wq, bq, (void*)Qb);
    gemm512<1, 0><<<gg, gb, 0, stream>>>((const void*)q, Wk, bk, (void*)Kb);
    gemm512<2, 0><<<gg, gb, 0, stream>>>((const void*)q, Wv, bv, (void*)Vt);

    dim3 ga(64, 16);
    attn64<<<ga, gb, 0, stream>>>(Qb, Kb, Vt, Mg);

    gemm512<0, 1><<<gg, gb, 0, stream>>>((const void*)Mg, Wo, bo, d_out);
}

// Round 3
// 291.216 us; speedup vs baseline: 1.2928x; 1.2928x over previous
//
#include <hip/hip_runtime.h>
#include <hip/hip_bf16.h>
#include <math.h>

typedef __attribute__((ext_vector_type(8))) short bf16x8;
typedef __attribute__((ext_vector_type(4))) float f32x4;

__device__ __forceinline__ unsigned short f2bf(float f) {
    union { float f; unsigned int u; } v; v.f = f;
    unsigned int u = v.u;
    u += 0x7fffu + ((u >> 16) & 1u);   // round-to-nearest-even
    return (unsigned short)(u >> 16);
}

// ---------------------------------------------------------------------------
// Shared GEMM body: C[m][n] = sum_k A[m][k] * W[n][k] + bias[n]
// M=8192, N=512, K=512. 128x128 tile, BK=32, 256 threads (4 waves 2x2).
// ---------------------------------------------------------------------------
template<int A_BF16>
__device__ __forceinline__ void gemm_body(const void* Ap, const float* W,
                                          f32x4 (&acc)[4][4],
                                          unsigned short (*As)[40], unsigned short (*Bs)[40],
                                          int bm, int bn, int t)
{
    constexpr int Kdim = 512;
    const int lane = t & 63, g = lane >> 4, c = lane & 15;
    const int w = t >> 6, wr = w >> 1, wc = w & 1;

    for (int k0 = 0; k0 < Kdim; k0 += 32) {
        __syncthreads();
        if (A_BF16) {
            const unsigned short* A = (const unsigned short*)Ap;
            int cc = (t & 3) * 8, r0 = t >> 2;
            for (int p = 0; p < 2; ++p) {
                int r = r0 + p * 64;
                uint4 v = *(const uint4*)(A + (size_t)(bm + r) * Kdim + k0 + cc);
                *(uint4*)&As[r][cc] = v;
            }
        } else {
            const float* A = (const float*)Ap;
            int c4 = (t & 7) * 4, r0 = t >> 3;
            for (int p = 0; p < 4; ++p) {
                int r = r0 + p * 32;
                float4 v = *(const float4*)(A + (size_t)(bm + r) * Kdim + k0 + c4);
                ushort4 hv;
                hv.x = f2bf(v.x); hv.y = f2bf(v.y); hv.z = f2bf(v.z); hv.w = f2bf(v.w);
                *(ushort4*)&As[r][c4] = hv;
            }
        }
        {
            int c4 = (t & 7) * 4, r0 = t >> 3;
            for (int p = 0; p < 4; ++p) {
                int r = r0 + p * 32;
                float4 v = *(const float4*)(W + (size_t)(bn + r) * Kdim + k0 + c4);
                ushort4 hv;
                hv.x = f2bf(v.x); hv.y = f2bf(v.y); hv.z = f2bf(v.z); hv.w = f2bf(v.w);
                *(ushort4*)&Bs[r][c4] = hv;
            }
        }
        __syncthreads();
        bf16x8 af[4], bfr[4];
        for (int i = 0; i < 4; ++i)
            af[i] = *(const bf16x8*)&As[wr * 64 + i * 16 + c][g * 8];
        for (int j = 0; j < 4; ++j)
            bfr[j] = *(const bf16x8*)&Bs[wc * 64 + j * 16 + c][g * 8];
        for (int i = 0; i < 4; ++i)
            for (int j = 0; j < 4; ++j)
                acc[i][j] = __builtin_amdgcn_mfma_f32_16x16x32_bf16(af[i], bfr[j], acc[i][j], 0, 0, 0);
    }
}

// Fused Q/K/V projections: blockIdx.z selects weight set. q fp32 input.
// Q,K out: bf16 [b*8+h][s][64]; V out: bf16 transposed [b*8+h][64][s].
__global__ __launch_bounds__(256, 2)
void gemm_qkv(const float* __restrict__ q,
              const float* __restrict__ Wq, const float* __restrict__ bq,
              const float* __restrict__ Wk, const float* __restrict__ bk,
              const float* __restrict__ Wv, const float* __restrict__ bv,
              unsigned short* __restrict__ Qo, unsigned short* __restrict__ Ko,
              unsigned short* __restrict__ Vo)
{
    __shared__ unsigned short As[128][40];
    __shared__ unsigned short Bs[128][40];
    const int t = threadIdx.x, z = blockIdx.z;
    const int lane = t & 63, g = lane >> 4, c = lane & 15;
    const int w = t >> 6, wr = w >> 1, wc = w & 1;
    const int bm = blockIdx.x * 128, bn = blockIdx.y * 128;

    const float* W    = (z == 0) ? Wq : (z == 1) ? Wk : Wv;
    const float* bias = (z == 0) ? bq : (z == 1) ? bk : bv;
    unsigned short* Out = (z == 0) ? Qo : (z == 1) ? Ko : Vo;

    f32x4 acc[4][4] = {};
    gemm_body<0>((const void*)q, W, acc, As, Bs, bm, bn, t);

    float bv4[4];
    for (int j = 0; j < 4; ++j) bv4[j] = bias[bn + wc * 64 + j * 16 + c];
    for (int i = 0; i < 4; ++i)
        for (int j = 0; j < 4; ++j)
            for (int r = 0; r < 4; ++r) {
                int m = bm + wr * 64 + i * 16 + 4 * g + r;
                int n = bn + wc * 64 + j * 16 + c;
                float val = acc[i][j][r] + bv4[j];
                int b = m >> 12, s = m & 4095, h = n >> 6, d = n & 63;
                if (z < 2)
                    Out[((((size_t)b * 8 + h) * 4096 + s) << 6) + d] = f2bf(val);
                else
                    Out[(((size_t)b * 8 + h) * 64 + d) * 4096 + s] = f2bf(val);
            }
}

// Output projection: A bf16 [8192][512], out fp32 [8192][512].
__global__ __launch_bounds__(256, 2)
void gemm_out(const unsigned short* __restrict__ A, const float* __restrict__ W,
              const float* __restrict__ bias, float* __restrict__ Out)
{
    __shared__ unsigned short As[128][40];
    __shared__ unsigned short Bs[128][40];
    const int t = threadIdx.x;
    const int lane = t & 63, g = lane >> 4, c = lane & 15;
    const int w = t >> 6, wr = w >> 1, wc = w & 1;
    const int bm = blockIdx.x * 128, bn = blockIdx.y * 128;

    f32x4 acc[4][4] = {};
    gemm_body<1>((const void*)A, W, acc, As, Bs, bm, bn, t);

    float bv4[4];
    for (int j = 0; j < 4; ++j) bv4[j] = bias[bn + wc * 64 + j * 16 + c];
    for (int i = 0; i < 4; ++i)
        for (int j = 0; j < 4; ++j)
            for (int r = 0; r < 4; ++r) {
                int m = bm + wr * 64 + i * 16 + 4 * g + r;
                int n = bn + wc * 64 + j * 16 + c;
                Out[(size_t)m * 512 + n] = acc[i][j][r] + bv4[j];
            }
}

// ---------------------------------------------------------------------------
// Flash attention fwd. Q,K: [16][4096][64] bf16; VT: [16][64][4096] bf16.
// 4 waves, 64 Q-rows (16/wave), KV-tile 64. Deferred-rescale online softmax
// (exp2 domain), per-lane l accumulation, reg-staged K/V prefetch.
// ---------------------------------------------------------------------------
__global__ __launch_bounds__(256, 2)
void attn64(const unsigned short* __restrict__ Q, const unsigned short* __restrict__ Kh,
            const unsigned short* __restrict__ VT, unsigned short* __restrict__ Mo)
{
    __shared__ unsigned short Ks[64][66];   // stride 33 dw (odd): <=4-way frag reads
    __shared__ unsigned short Vs[64][66];
    __shared__ unsigned short Ps[64][66];

    const int t = threadIdx.x, w = t >> 6, lane = t & 63, g = lane >> 4, c = lane & 15;
    const int bh = blockIdx.y;
    const int q0 = blockIdx.x * 64;
    const unsigned short* Qb = Q + (size_t)bh * 4096 * 64;
    const unsigned short* Kb = Kh + (size_t)bh * 4096 * 64;
    const unsigned short* Vb = VT + (size_t)bh * 64 * 4096;

    bf16x8 qf[2];
    {
        int qr = q0 + w * 16 + c;
        qf[0] = *(const bf16x8*)(Qb + (size_t)qr * 64 + g * 8);
        qf[1] = *(const bf16x8*)(Qb + (size_t)qr * 64 + 32 + g * 8);
    }

    f32x4 o[4] = {};
    float m2[4], lsum[4];
    for (int r = 0; r < 4; ++r) { m2[r] = -3.0e38f; lsum[r] = 0.f; }

    const int srow = t >> 2, scol = (t & 3) * 16;
    const unsigned short* kp0 = Kb + (size_t)srow * 64 + scol;
    const unsigned short* vp0 = Vb + (size_t)srow * 4096 + scol;

    // prefetch tile 0 into regs
    uint4 ka0 = *(const uint4*)(kp0);
    uint4 ka1 = *(const uint4*)(kp0 + 8);
    uint4 va0 = *(const uint4*)(vp0);
    uint4 va1 = *(const uint4*)(vp0 + 8);

    const float sc2 = 0.125f * 1.44269504f;   // scale * log2(e): exp2 domain
    const float THR = 10.f;                   // p bounded by 2^10

    for (int jt = 0; jt < 64; ++jt) {
        __syncthreads();
        // write prefetched tile to LDS
        *(uint4*)&Ks[srow][scol]     = ka0;
        *(uint4*)&Ks[srow][scol + 8] = ka1;
        *(uint4*)&Vs[srow][scol]     = va0;
        *(uint4*)&Vs[srow][scol + 8] = va1;
        // issue next tile's loads (land at the end of this iteration's compute)
        if (jt < 63) {
            const unsigned short* kp = kp0 + (size_t)(jt + 1) * 4096;
            ka0 = *(const uint4*)(kp);
            ka1 = *(const uint4*)(kp + 8);
            const unsigned short* vp = vp0 + (jt + 1) * 64;
            va0 = *(const uint4*)(vp);
            va1 = *(const uint4*)(vp + 8);
        }
        __syncthreads();

        // S = Q K^T (16 q-rows x 64 keys per wave), scaled to exp2 domain
        f32x4 s[4];
        for (int nt = 0; nt < 4; ++nt) {
            bf16x8 kf0 = *(const bf16x8*)&Ks[nt * 16 + c][g * 8];
            bf16x8 kf1 = *(const bf16x8*)&Ks[nt * 16 + c][32 + g * 8];
            f32x4 z = {};
            z = __builtin_amdgcn_mfma_f32_16x16x32_bf16(qf[0], kf0, z, 0, 0, 0);
            z = __builtin_amdgcn_mfma_f32_16x16x32_bf16(qf[1], kf1, z, 0, 0, 0);
            for (int r = 0; r < 4; ++r) s[nt][r] = z[r] * sc2;
        }

        // deferred-rescale check: per-lane partial max, wave-wide ballot
        float pmax[4];
        for (int r = 0; r < 4; ++r)
            pmax[r] = fmaxf(fmaxf(s[0][r], s[1][r]), fmaxf(s[2][r], s[3][r]));
        bool ok = (pmax[0] <= m2[0] + THR) && (pmax[1] <= m2[1] + THR) &&
                  (pmax[2] <= m2[2] + THR) && (pmax[3] <= m2[3] + THR);
        if (!__all(ok)) {
            // rare path: full cross-lane row max + rescale
            for (int mk = 1; mk < 16; mk <<= 1)
                for (int r = 0; r < 4; ++r)
                    pmax[r] = fmaxf(pmax[r], __shfl_xor(pmax[r], mk));
            float alpha[4];
            for (int r = 0; r < 4; ++r) {
                float mn = fmaxf(m2[r], pmax[r]);
                alpha[r] = exp2f(m2[r] - mn);
                m2[r] = mn;
                lsum[r] *= alpha[r];
            }
            for (int nt = 0; nt < 4; ++nt)
                for (int r = 0; r < 4; ++r)
                    o[nt][r] *= alpha[r];
        }

        // p = 2^(s - m); accumulate l per-lane; write P to LDS
        for (int nt = 0; nt < 4; ++nt)
            for (int r = 0; r < 4; ++r) {
                float p = exp2f(s[nt][r] - m2[r]);
                lsum[r] += p;
                Ps[w * 16 + 4 * g + r][nt * 16 + c] = f2bf(p);
            }
        bf16x8 pf0 = *(const bf16x8*)&Ps[w * 16 + c][g * 8];
        bf16x8 pf1 = *(const bf16x8*)&Ps[w * 16 + c][32 + g * 8];

        // O += P V
        for (int nt = 0; nt < 4; ++nt) {
            bf16x8 v0 = *(const bf16x8*)&Vs[nt * 16 + c][g * 8];
            bf16x8 v1 = *(const bf16x8*)&Vs[nt * 16 + c][32 + g * 8];
            o[nt] = __builtin_amdgcn_mfma_f32_16x16x32_bf16(pf0, v0, o[nt], 0, 0, 0);
            o[nt] = __builtin_amdgcn_mfma_f32_16x16x32_bf16(pf1, v1, o[nt], 0, 0, 0);
        }
    }

    // epilogue: reduce l across the 16 lanes of each row group, write O/l
    for (int mk = 1; mk < 16; mk <<= 1)
        for (int r = 0; r < 4; ++r)
            lsum[r] += __shfl_xor(lsum[r], mk);

    const int b = bh >> 3, h = bh & 7;
    for (int r = 0; r < 4; ++r) {
        float inv = 1.f / lsum[r];
        int m = b * 4096 + q0 + w * 16 + 4 * g + r;
        for (int nt = 0; nt < 4; ++nt) {
            int n = h * 64 + nt * 16 + c;
            Mo[(size_t)m * 512 + n] = f2bf(o[nt][r] * inv);
        }
    }
}

extern "C" void kernel_launch(void* const* d_in, const int* in_sizes, int n_in,
                              void* d_out, int out_size, void* d_ws, size_t ws_size,
                              hipStream_t stream) {
    const float* q  = (const float*)d_in[0];
    const float* Wq = (const float*)d_in[1];
    const float* bq = (const float*)d_in[2];
    const float* Wk = (const float*)d_in[3];
    const float* bk = (const float*)d_in[4];
    const float* Wv = (const float*)d_in[5];
    const float* bv = (const float*)d_in[6];
    const float* Wo = (const float*)d_in[7];
    const float* bo = (const float*)d_in[8];

    unsigned short* Qb = (unsigned short*)d_ws;            // 8 MB
    unsigned short* Kb = Qb + (size_t)16 * 4096 * 64;      // 8 MB
    unsigned short* Vt = Kb + (size_t)16 * 4096 * 64;      // 8 MB (V^T per head)
    unsigned short* Mg = Vt + (size_t)16 * 4096 * 64;      // merged bf16 [8192][512]

    dim3 gb(256);
    dim3 gqkv(64, 4, 3);
    gemm_qkv<<<gqkv, gb, 0, stream>>>(q, Wq, bq, Wk, bk, Wv, bv, Qb, Kb, Vt);

    dim3 ga(64, 16);
    attn64<<<ga, gb, 0, stream>>>(Qb, Kb, Vt, Mg);

    dim3 gg(64, 4);
    gemm_out<<<gg, gb, 0, stream>>>(Mg, Wo, bo, (float*)d_out);
}

// Round 4
// 230.485 us; speedup vs baseline: 1.6334x; 1.2635x over previous
//
#include <hip/hip_runtime.h>
#include <hip/hip_bf16.h>
#include <math.h>

typedef __attribute__((ext_vector_type(8))) short bf16x8;
typedef __attribute__((ext_vector_type(4))) short bf16x4;
typedef __attribute__((ext_vector_type(4))) float f32x4;

__device__ __forceinline__ unsigned short f2bf(float f) {
    union { float f; unsigned int u; } v; v.f = f;
    unsigned int u = v.u;
    u += 0x7fffu + ((u >> 16) & 1u);   // round-to-nearest-even
    return (unsigned short)(u >> 16);
}

__device__ __forceinline__ f32x4 mfma16(bf16x4 a, bf16x4 b, f32x4 c) {
#if __has_builtin(__builtin_amdgcn_mfma_f32_16x16x16bf16_1k)
    return __builtin_amdgcn_mfma_f32_16x16x16bf16_1k(a, b, c, 0, 0, 0);
#else
    asm volatile("v_mfma_f32_16x16x16_bf16 %0, %1, %2, %0\n\ts_nop 7"
                 : "+v"(c) : "v"(a), "v"(b));
    return c;
#endif
}

// pack two f32 -> one dword of 2 bf16 (RNE)
__device__ __forceinline__ unsigned packbf2(float a, float b) {
    __hip_bfloat162 h = __float22bfloat162_rn(float2{a, b});
    union { __hip_bfloat162 h; unsigned u; } v; v.h = h;
    return v.u;
}

// ---------------------------------------------------------------------------
// Shared GEMM body: C[m][n] = sum_k A[m][k] * W[n][k] + bias[n]
// M=8192, N=512, K=512. 128x128 tile, BK=32, 256 threads (4 waves 2x2).
// ---------------------------------------------------------------------------
template<int A_BF16>
__device__ __forceinline__ void gemm_body(const void* Ap, const float* W,
                                          f32x4 (&acc)[4][4],
                                          unsigned short (*As)[40], unsigned short (*Bs)[40],
                                          int bm, int bn, int t)
{
    constexpr int Kdim = 512;
    const int lane = t & 63, g = lane >> 4, c = lane & 15;
    const int w = t >> 6, wr = w >> 1, wc = w & 1;

    for (int k0 = 0; k0 < Kdim; k0 += 32) {
        __syncthreads();
        if (A_BF16) {
            const unsigned short* A = (const unsigned short*)Ap;
            int cc = (t & 3) * 8, r0 = t >> 2;
            for (int p = 0; p < 2; ++p) {
                int r = r0 + p * 64;
                uint4 v = *(const uint4*)(A + (size_t)(bm + r) * Kdim + k0 + cc);
                *(uint4*)&As[r][cc] = v;
            }
        } else {
            const float* A = (const float*)Ap;
            int c4 = (t & 7) * 4, r0 = t >> 3;
            for (int p = 0; p < 4; ++p) {
                int r = r0 + p * 32;
                float4 v = *(const float4*)(A + (size_t)(bm + r) * Kdim + k0 + c4);
                ushort4 hv;
                hv.x = f2bf(v.x); hv.y = f2bf(v.y); hv.z = f2bf(v.z); hv.w = f2bf(v.w);
                *(ushort4*)&As[r][c4] = hv;
            }
        }
        {
            int c4 = (t & 7) * 4, r0 = t >> 3;
            for (int p = 0; p < 4; ++p) {
                int r = r0 + p * 32;
                float4 v = *(const float4*)(W + (size_t)(bn + r) * Kdim + k0 + c4);
                ushort4 hv;
                hv.x = f2bf(v.x); hv.y = f2bf(v.y); hv.z = f2bf(v.z); hv.w = f2bf(v.w);
                *(ushort4*)&Bs[r][c4] = hv;
            }
        }
        __syncthreads();
        bf16x8 af[4], bfr[4];
        for (int i = 0; i < 4; ++i)
            af[i] = *(const bf16x8*)&As[wr * 64 + i * 16 + c][g * 8];
        for (int j = 0; j < 4; ++j)
            bfr[j] = *(const bf16x8*)&Bs[wc * 64 + j * 16 + c][g * 8];
        for (int i = 0; i < 4; ++i)
            for (int j = 0; j < 4; ++j)
                acc[i][j] = __builtin_amdgcn_mfma_f32_16x16x32_bf16(af[i], bfr[j], acc[i][j], 0, 0, 0);
    }
}

// Fused Q/K/V projections: blockIdx.z selects weight set. q fp32 input.
__global__ __launch_bounds__(256, 2)
void gemm_qkv(const float* __restrict__ q,
              const float* __restrict__ Wq, const float* __restrict__ bq,
              const float* __restrict__ Wk, const float* __restrict__ bk,
              const float* __restrict__ Wv, const float* __restrict__ bv,
              unsigned short* __restrict__ Qo, unsigned short* __restrict__ Ko,
              unsigned short* __restrict__ Vo)
{
    __shared__ unsigned short As[128][40];
    __shared__ unsigned short Bs[128][40];
    const int t = threadIdx.x, z = blockIdx.z;
    const int lane = t & 63, g = lane >> 4, c = lane & 15;
    const int w = t >> 6, wr = w >> 1, wc = w & 1;
    const int bm = blockIdx.x * 128, bn = blockIdx.y * 128;

    const float* W    = (z == 0) ? Wq : (z == 1) ? Wk : Wv;
    const float* bias = (z == 0) ? bq : (z == 1) ? bk : bv;
    unsigned short* Out = (z == 0) ? Qo : (z == 1) ? Ko : Vo;

    f32x4 acc[4][4] = {};
    gemm_body<0>((const void*)q, W, acc, As, Bs, bm, bn, t);

    float bv4[4];
    for (int j = 0; j < 4; ++j) bv4[j] = bias[bn + wc * 64 + j * 16 + c];
    for (int i = 0; i < 4; ++i)
        for (int j = 0; j < 4; ++j)
            for (int r = 0; r < 4; ++r) {
                int m = bm + wr * 64 + i * 16 + 4 * g + r;
                int n = bn + wc * 64 + j * 16 + c;
                float val = acc[i][j][r] + bv4[j];
                int b = m >> 12, s = m & 4095, h = n >> 6, d = n & 63;
                if (z < 2)
                    Out[((((size_t)b * 8 + h) * 4096 + s) << 6) + d] = f2bf(val);
                else
                    Out[(((size_t)b * 8 + h) * 64 + d) * 4096 + s] = f2bf(val);
            }
}

// Output projection: A bf16 [8192][512], out fp32 [8192][512].
__global__ __launch_bounds__(256, 2)
void gemm_out(const unsigned short* __restrict__ A, const float* __restrict__ W,
              const float* __restrict__ bias, float* __restrict__ Out)
{
    __shared__ unsigned short As[128][40];
    __shared__ unsigned short Bs[128][40];
    const int t = threadIdx.x;
    const int lane = t & 63, g = lane >> 4, c = lane & 15;
    const int w = t >> 6, wr = w >> 1, wc = w & 1;
    const int bm = blockIdx.x * 128, bn = blockIdx.y * 128;

    f32x4 acc[4][4] = {};
    gemm_body<1>((const void*)A, W, acc, As, Bs, bm, bn, t);

    float bv4[4];
    for (int j = 0; j < 4; ++j) bv4[j] = bias[bn + wc * 64 + j * 16 + c];
    for (int i = 0; i < 4; ++i)
        for (int j = 0; j < 4; ++j)
            for (int r = 0; r < 4; ++r) {
                int m = bm + wr * 64 + i * 16 + 4 * g + r;
                int n = bn + wc * 64 + j * 16 + c;
                Out[(size_t)m * 512 + n] = acc[i][j][r] + bv4[j];
            }
}

// ---------------------------------------------------------------------------
// Flash attention fwd. Q,K: [16][4096][64] bf16; VT: [16][64][4096] bf16.
// 4 waves, 64 Q-rows (16/wave), KV-tile 64.
// Swapped QK^T (mfma(K,Q)) -> lane(g,c) holds S[q=c][key=16nt+4g+r], which
// is EXACTLY the A-fragment of mfma_16x16x16 -> PV needs no P movement.
// Per-lane softmax state (q-row = c), deferred rescale, reg-staged prefetch.
// ---------------------------------------------------------------------------
__global__ __launch_bounds__(256, 2)
void attn64(const unsigned short* __restrict__ Q, const unsigned short* __restrict__ Kh,
            const unsigned short* __restrict__ VT, unsigned short* __restrict__ Mo)
{
    __shared__ unsigned short Ks[64][72];   // 144B rows: 16B-aligned, conflict-optimal
    __shared__ unsigned short Vs[64][72];   // [d][key]

    const int t = threadIdx.x, w = t >> 6, lane = t & 63, g = lane >> 4, c = lane & 15;
    const int bh = blockIdx.y;
    const int q0 = blockIdx.x * 64;
    const unsigned short* Qb = Q + (size_t)bh * 4096 * 64;
    const unsigned short* Kb = Kh + (size_t)bh * 4096 * 64;
    const unsigned short* Vb = VT + (size_t)bh * 64 * 4096;

    // Q fragments hoisted: wave's q-rows are w*16 + c
    bf16x8 qf[2];
    {
        int qr = q0 + w * 16 + c;
        qf[0] = *(const bf16x8*)(Qb + (size_t)qr * 64 + g * 8);
        qf[1] = *(const bf16x8*)(Qb + (size_t)qr * 64 + 32 + g * 8);
    }

    f32x4 o[4] = {};          // o[nd][r] = O[q-local 4g+r][d = nd*16+c]
    float nm2 = 0.f;          // -m for this lane's q-row (c); exp2 domain
    float lsum = 0.f;         // per-lane partial over this lane's 16 keys/tile

    const int srow = t >> 2, scol = (t & 3) * 16;
    const unsigned short* kp0 = Kb + (size_t)srow * 64 + scol;
    const unsigned short* vp0 = Vb + (size_t)srow * 4096 + scol;

    uint4 ka0 = *(const uint4*)(kp0);
    uint4 ka1 = *(const uint4*)(kp0 + 8);
    uint4 va0 = *(const uint4*)(vp0);
    uint4 va1 = *(const uint4*)(vp0 + 8);

    const float sc2 = 0.125f * 1.44269504f;   // scale * log2(e)
    const float THR = 10.f;                   // p bounded by 2^10

    for (int jt = 0; jt < 64; ++jt) {
        __syncthreads();
        *(uint4*)&Ks[srow][scol]     = ka0;
        *(uint4*)&Ks[srow][scol + 8] = ka1;
        *(uint4*)&Vs[srow][scol]     = va0;
        *(uint4*)&Vs[srow][scol + 8] = va1;
        if (jt < 63) {
            const unsigned short* kp = kp0 + (size_t)(jt + 1) * 4096;
            ka0 = *(const uint4*)(kp);
            ka1 = *(const uint4*)(kp + 8);
            const unsigned short* vp = vp0 + (jt + 1) * 64;
            va0 = *(const uint4*)(vp);
            va1 = *(const uint4*)(vp + 8);
        }
        __syncthreads();

        // S^T = K Q^T: t4[nt][r] = S[q=c][key=16nt+4g+r] * sc2 - m
        f32x4 t4[4];
        for (int nt = 0; nt < 4; ++nt) {
            bf16x8 kf0 = *(const bf16x8*)&Ks[nt * 16 + c][g * 8];
            bf16x8 kf1 = *(const bf16x8*)&Ks[nt * 16 + c][32 + g * 8];
            f32x4 z = {};
            z = __builtin_amdgcn_mfma_f32_16x16x32_bf16(kf0, qf[0], z, 0, 0, 0);
            z = __builtin_amdgcn_mfma_f32_16x16x32_bf16(kf1, qf[1], z, 0, 0, 0);
            for (int r = 0; r < 4; ++r) t4[nt][r] = fmaf(z[r], sc2, nm2);
        }

        // deferred rescale: per-lane max over this lane's 16 keys
        float tm = fmaxf(fmaxf(fmaxf(t4[0][0], t4[0][1]), fmaxf(t4[0][2], t4[0][3])),
                  fmaxf(fmaxf(fmaxf(t4[1][0], t4[1][1]), fmaxf(t4[1][2], t4[1][3])),
                  fmaxf(fmaxf(fmaxf(t4[2][0], t4[2][1]), fmaxf(t4[2][2], t4[2][3])),
                        fmaxf(fmaxf(t4[3][0], t4[3][1]), fmaxf(t4[3][2], t4[3][3])))));
        if (!__all(tm <= THR)) {
            // rare: reduce max across the 4 g-groups (same q-row c)
            float pm = tm;
            pm = fmaxf(pm, __shfl_xor(pm, 16));
            pm = fmaxf(pm, __shfl_xor(pm, 32));
            float dm = fmaxf(pm, 0.f);        // shift for q-row c
            nm2 -= dm;
            float alpha = exp2f(-dm);
            lsum *= alpha;
            for (int nt = 0; nt < 4; ++nt)
                for (int r = 0; r < 4; ++r) t4[nt][r] -= dm;
            // o rows are q-local 4g+r -> fetch alpha from lane 4g+r
            for (int r = 0; r < 4; ++r) {
                float ar = __shfl(alpha, 4 * g + r);
                for (int nd = 0; nd < 4; ++nd) o[nd][r] *= ar;
            }
        }

        // p = 2^t, accumulate l, pack to A-fragments of mfma16
        bf16x4 pf[4];
        for (int nt = 0; nt < 4; ++nt) {
            float p0 = exp2f(t4[nt][0]), p1 = exp2f(t4[nt][1]);
            float p2 = exp2f(t4[nt][2]), p3 = exp2f(t4[nt][3]);
            lsum += (p0 + p1) + (p2 + p3);
            union { unsigned u[2]; bf16x4 v; } pk;
            pk.u[0] = packbf2(p0, p1);
            pk.u[1] = packbf2(p2, p3);
            pf[nt] = pk.v;
        }

        // O += P V: o[nd] accumulates over the 4 key-blocks nt
        for (int nd = 0; nd < 4; ++nd)
            for (int nt = 0; nt < 4; ++nt) {
                bf16x4 vf = *(const bf16x4*)&Vs[nd * 16 + c][nt * 16 + 4 * g];
                o[nd] = mfma16(pf[nt], vf, o[nd]);
            }
    }

    // reduce l across g-groups (keys partition), broadcast to o-rows
    lsum += __shfl_xor(lsum, 16);
    lsum += __shfl_xor(lsum, 32);

    const int b = bh >> 3, h = bh & 7;
    for (int r = 0; r < 4; ++r) {
        float lr = __shfl(lsum, 4 * g + r);   // l for q-local row 4g+r
        float inv = 1.f / lr;
        int m = b * 4096 + q0 + w * 16 + 4 * g + r;
        for (int nd = 0; nd < 4; ++nd) {
            int n = h * 64 + nd * 16 + c;
            Mo[(size_t)m * 512 + n] = f2bf(o[nd][r] * inv);
        }
    }
}

extern "C" void kernel_launch(void* const* d_in, const int* in_sizes, int n_in,
                              void* d_out, int out_size, void* d_ws, size_t ws_size,
                              hipStream_t stream) {
    const float* q  = (const float*)d_in[0];
    const float* Wq = (const float*)d_in[1];
    const float* bq = (const float*)d_in[2];
    const float* Wk = (const float*)d_in[3];
    const float* bk = (const float*)d_in[4];
    const float* Wv = (const float*)d_in[5];
    const float* bv = (const float*)d_in[6];
    const float* Wo = (const float*)d_in[7];
    const float* bo = (const float*)d_in[8];

    unsigned short* Qb = (unsigned short*)d_ws;            // 8 MB
    unsigned short* Kb = Qb + (size_t)16 * 4096 * 64;      // 8 MB
    unsigned short* Vt = Kb + (size_t)16 * 4096 * 64;      // 8 MB (V^T per head)
    unsigned short* Mg = Vt + (size_t)16 * 4096 * 64;      // merged bf16 [8192][512]

    dim3 gb(256);
    dim3 gqkv(64, 4, 3);
    gemm_qkv<<<gqkv, gb, 0, stream>>>(q, Wq, bq, Wk, bk, Wv, bv, Qb, Kb, Vt);

    dim3 ga(64, 16);
    attn64<<<ga, gb, 0, stream>>>(Qb, Kb, Vt, Mg);

    dim3 gg(64, 4);
    gemm_out<<<gg, gb, 0, stream>>>(Mg, Wo, bo, (float*)d_out);
}

// Round 5
// 200.659 us; speedup vs baseline: 1.8762x; 1.1486x over previous
//
#include <hip/hip_runtime.h>
#include <hip/hip_bf16.h>
#include <math.h>

typedef __attribute__((ext_vector_type(8))) short bf16x8;
typedef __attribute__((ext_vector_type(4))) short bf16x4;
typedef __attribute__((ext_vector_type(4))) float f32x4;

__device__ __forceinline__ unsigned short f2bf(float f) {
    union { float f; unsigned int u; } v; v.f = f;
    unsigned int u = v.u;
    u += 0x7fffu + ((u >> 16) & 1u);   // round-to-nearest-even
    return (unsigned short)(u >> 16);
}

__device__ __forceinline__ f32x4 mfma16(bf16x4 a, bf16x4 b, f32x4 c) {
#if __has_builtin(__builtin_amdgcn_mfma_f32_16x16x16bf16_1k)
    return __builtin_amdgcn_mfma_f32_16x16x16bf16_1k(a, b, c, 0, 0, 0);
#else
    asm volatile("v_mfma_f32_16x16x16_bf16 %0, %1, %2, %0\n\ts_nop 7"
                 : "+v"(c) : "v"(a), "v"(b));
    return c;
#endif
}

__device__ __forceinline__ unsigned packbf2(float a, float b) {
    __hip_bfloat162 h = __float22bfloat162_rn(float2{a, b});
    union { __hip_bfloat162 h; unsigned u; } v; v.h = h;
    return v.u;
}

__device__ __forceinline__ float fmax3(float a, float b, float c) {
    return fmaxf(fmaxf(a, b), c);   // clang fuses to v_max3_f32
}

// ---------------------------------------------------------------------------
// Shared GEMM body: C[m][n] = sum_k A[m][k] * W[n][k] + bias[n]
// M=8192, N=512, K=512. 128x128 tile, BK=32, 256 threads (4 waves 2x2).
// Register-prefetched staging: loads for k-tile t+1 issue AFTER the second
// barrier (so the compiler's vmcnt(0)-before-barrier drain doesn't expose
// their latency -- they fly across the 16-MFMA compute phase).
// ---------------------------------------------------------------------------
template<int A_BF16>
__device__ __forceinline__ void gemm_body(const void* Ap, const float* W,
                                          f32x4 (&acc)[4][4],
                                          unsigned short (*As)[40], unsigned short (*Bs)[40],
                                          int bm, int bn, int t)
{
    constexpr int Kdim = 512;
    const int lane = t & 63, g = lane >> 4, c = lane & 15;
    const int w = t >> 6, wr = w >> 1, wc = w & 1;

    uint4  paB[2];
    float4 paF[4];
    float4 pw[4];
    const int ccB = (t & 3) * 8, r0B = t >> 2;
    const int c4  = (t & 7) * 4, r0F = t >> 3;

    // prefetch k-tile 0
    if (A_BF16) {
        const unsigned short* A = (const unsigned short*)Ap;
        for (int p = 0; p < 2; ++p)
            paB[p] = *(const uint4*)(A + (size_t)(bm + r0B + p * 64) * Kdim + ccB);
    } else {
        const float* A = (const float*)Ap;
        for (int p = 0; p < 4; ++p)
            paF[p] = *(const float4*)(A + (size_t)(bm + r0F + p * 32) * Kdim + c4);
    }
    for (int p = 0; p < 4; ++p)
        pw[p] = *(const float4*)(W + (size_t)(bn + r0F + p * 32) * Kdim + c4);

    for (int k0 = 0; k0 < Kdim; k0 += 32) {
        __syncthreads();
        if (A_BF16) {
            for (int p = 0; p < 2; ++p)
                *(uint4*)&As[r0B + p * 64][ccB] = paB[p];
        } else {
            for (int p = 0; p < 4; ++p) {
                float4 v = paF[p];
                ushort4 hv;
                hv.x = f2bf(v.x); hv.y = f2bf(v.y); hv.z = f2bf(v.z); hv.w = f2bf(v.w);
                *(ushort4*)&As[r0F + p * 32][c4] = hv;
            }
        }
        for (int p = 0; p < 4; ++p) {
            float4 v = pw[p];
            ushort4 hv;
            hv.x = f2bf(v.x); hv.y = f2bf(v.y); hv.z = f2bf(v.z); hv.w = f2bf(v.w);
            *(ushort4*)&Bs[r0F + p * 32][c4] = hv;
        }
        __syncthreads();
        // issue next tile's loads AFTER the barrier: latency hides under MFMA
        if (k0 + 32 < Kdim) {
            const int kn = k0 + 32;
            if (A_BF16) {
                const unsigned short* A = (const unsigned short*)Ap;
                for (int p = 0; p < 2; ++p)
                    paB[p] = *(const uint4*)(A + (size_t)(bm + r0B + p * 64) * Kdim + kn + ccB);
            } else {
                const float* A = (const float*)Ap;
                for (int p = 0; p < 4; ++p)
                    paF[p] = *(const float4*)(A + (size_t)(bm + r0F + p * 32) * Kdim + kn + c4);
            }
            for (int p = 0; p < 4; ++p)
                pw[p] = *(const float4*)(W + (size_t)(bn + r0F + p * 32) * Kdim + kn + c4);
        }
        bf16x8 af[4], bfr[4];
        for (int i = 0; i < 4; ++i)
            af[i] = *(const bf16x8*)&As[wr * 64 + i * 16 + c][g * 8];
        for (int j = 0; j < 4; ++j)
            bfr[j] = *(const bf16x8*)&Bs[wc * 64 + j * 16 + c][g * 8];
        for (int i = 0; i < 4; ++i)
            for (int j = 0; j < 4; ++j)
                acc[i][j] = __builtin_amdgcn_mfma_f32_16x16x32_bf16(af[i], bfr[j], acc[i][j], 0, 0, 0);
    }
}

// Fused Q/K/V projections: blockIdx.z selects weight set. q fp32 input.
__global__ __launch_bounds__(256, 2)
void gemm_qkv(const float* __restrict__ q,
              const float* __restrict__ Wq, const float* __restrict__ bq,
              const float* __restrict__ Wk, const float* __restrict__ bk,
              const float* __restrict__ Wv, const float* __restrict__ bv,
              unsigned short* __restrict__ Qo, unsigned short* __restrict__ Ko,
              unsigned short* __restrict__ Vo)
{
    __shared__ unsigned short As[128][40];
    __shared__ unsigned short Bs[128][40];
    const int t = threadIdx.x, z = blockIdx.z;
    const int lane = t & 63, g = lane >> 4, c = lane & 15;
    const int w = t >> 6, wr = w >> 1, wc = w & 1;
    const int bm = blockIdx.x * 128, bn = blockIdx.y * 128;

    const float* W    = (z == 0) ? Wq : (z == 1) ? Wk : Wv;
    const float* bias = (z == 0) ? bq : (z == 1) ? bk : bv;
    unsigned short* Out = (z == 0) ? Qo : (z == 1) ? Ko : Vo;

    f32x4 acc[4][4] = {};
    gemm_body<0>((const void*)q, W, acc, As, Bs, bm, bn, t);

    float bv4[4];
    for (int j = 0; j < 4; ++j) bv4[j] = bias[bn + wc * 64 + j * 16 + c];
    for (int i = 0; i < 4; ++i)
        for (int j = 0; j < 4; ++j)
            for (int r = 0; r < 4; ++r) {
                int m = bm + wr * 64 + i * 16 + 4 * g + r;
                int n = bn + wc * 64 + j * 16 + c;
                float val = acc[i][j][r] + bv4[j];
                int b = m >> 12, s = m & 4095, h = n >> 6, d = n & 63;
                if (z < 2)
                    Out[((((size_t)b * 8 + h) * 4096 + s) << 6) + d] = f2bf(val);
                else
                    Out[(((size_t)b * 8 + h) * 64 + d) * 4096 + s] = f2bf(val);
            }
}

// Output projection: A bf16 [8192][512], out fp32 [8192][512].
__global__ __launch_bounds__(256, 2)
void gemm_out(const unsigned short* __restrict__ A, const float* __restrict__ W,
              const float* __restrict__ bias, float* __restrict__ Out)
{
    __shared__ unsigned short As[128][40];
    __shared__ unsigned short Bs[128][40];
    const int t = threadIdx.x;
    const int lane = t & 63, g = lane >> 4, c = lane & 15;
    const int w = t >> 6, wr = w >> 1, wc = w & 1;
    const int bm = blockIdx.x * 128, bn = blockIdx.y * 128;

    f32x4 acc[4][4] = {};
    gemm_body<1>((const void*)A, W, acc, As, Bs, bm, bn, t);

    float bv4[4];
    for (int j = 0; j < 4; ++j) bv4[j] = bias[bn + wc * 64 + j * 16 + c];
    for (int i = 0; i < 4; ++i)
        for (int j = 0; j < 4; ++j)
            for (int r = 0; r < 4; ++r) {
                int m = bm + wr * 64 + i * 16 + 4 * g + r;
                int n = bn + wc * 64 + j * 16 + c;
                Out[(size_t)m * 512 + n] = acc[i][j][r] + bv4[j];
            }
}

// ---------------------------------------------------------------------------
// Flash attention fwd. Q,K: [16][4096][64] bf16; VT: [16][64][4096] bf16.
// 4 waves, 64 Q-rows (16/wave), KV-tile 64. Swapped QK^T; per-lane softmax;
// l via ones-column MFMA (consistent with bf16 P numerator); prefetch issued
// after barrier 2; bijective XCD swizzle (2 heads per XCD L2).
// ---------------------------------------------------------------------------
__global__ __launch_bounds__(256, 2)
void attn64(const unsigned short* __restrict__ Q, const unsigned short* __restrict__ Kh,
            const unsigned short* __restrict__ VT, unsigned short* __restrict__ Mo)
{
    __shared__ unsigned short Ks[64][72];
    __shared__ unsigned short Vs[64][72];

    const int t = threadIdx.x, w = t >> 6, lane = t & 63, g = lane >> 4, c = lane & 15;
    // XCD-aware swizzle: 1024 blocks, 8 XCDs, 1024%8==0 -> bijective.
    const int idp = (blockIdx.x & 7) * 128 + (blockIdx.x >> 3);
    const int bh = idp >> 6;
    const int q0 = (idp & 63) * 64;
    const unsigned short* Qb = Q + (size_t)bh * 4096 * 64;
    const unsigned short* Kb = Kh + (size_t)bh * 4096 * 64;
    const unsigned short* Vb = VT + (size_t)bh * 64 * 4096;

    bf16x8 qf[2];
    {
        int qr = q0 + w * 16 + c;
        qf[0] = *(const bf16x8*)(Qb + (size_t)qr * 64 + g * 8);
        qf[1] = *(const bf16x8*)(Qb + (size_t)qr * 64 + 32 + g * 8);
    }

    f32x4 o[4] = {};          // o[nd][r] = O[q-local 4g+r][d = nd*16+c]
    f32x4 lacc = {};          // lacc[r] = l for q-row 4g+r (ones-column MFMA)
    float nm2 = 0.f;          // -m for this lane's q-row (c); exp2 domain

    bf16x4 ones;
    ones[0] = ones[1] = ones[2] = ones[3] = (short)0x3F80;   // bf16 1.0

    const int srow = t >> 2, scol = (t & 3) * 16;
    const unsigned short* kp0 = Kb + (size_t)srow * 64 + scol;
    const unsigned short* vp0 = Vb + (size_t)srow * 4096 + scol;

    uint4 ka0 = *(const uint4*)(kp0);
    uint4 ka1 = *(const uint4*)(kp0 + 8);
    uint4 va0 = *(const uint4*)(vp0);
    uint4 va1 = *(const uint4*)(vp0 + 8);

    const float sc2 = 0.125f * 1.44269504f;   // scale * log2(e)
    const float THR = 10.f;                   // p bounded by 2^10

    for (int jt = 0; jt < 64; ++jt) {
        __syncthreads();
        *(uint4*)&Ks[srow][scol]     = ka0;
        *(uint4*)&Ks[srow][scol + 8] = ka1;
        *(uint4*)&Vs[srow][scol]     = va0;
        *(uint4*)&Vs[srow][scol + 8] = va1;
        __syncthreads();
        // issue next tile's loads AFTER the barrier: they fly across compute
        if (jt < 63) {
            const unsigned short* kp = kp0 + (size_t)(jt + 1) * 4096;
            ka0 = *(const uint4*)(kp);
            ka1 = *(const uint4*)(kp + 8);
            const unsigned short* vp = vp0 + (jt + 1) * 64;
            va0 = *(const uint4*)(vp);
            va1 = *(const uint4*)(vp + 8);
        }

        // S^T = K Q^T: t4[nt][r] = S[q=c][key=16nt+4g+r] * sc2 - m
        f32x4 t4[4];
        for (int nt = 0; nt < 4; ++nt) {
            bf16x8 kf0 = *(const bf16x8*)&Ks[nt * 16 + c][g * 8];
            bf16x8 kf1 = *(const bf16x8*)&Ks[nt * 16 + c][32 + g * 8];
            f32x4 z = {};
            z = __builtin_amdgcn_mfma_f32_16x16x32_bf16(kf0, qf[0], z, 0, 0, 0);
            z = __builtin_amdgcn_mfma_f32_16x16x32_bf16(kf1, qf[1], z, 0, 0, 0);
            for (int r = 0; r < 4; ++r) t4[nt][r] = fmaf(z[r], sc2, nm2);
        }

        // per-lane max of 16 via max3 tree (7 ops)
        float ma = fmax3(t4[0][0], t4[0][1], t4[0][2]);
        float mb = fmax3(t4[0][3], t4[1][0], t4[1][1]);
        float mc = fmax3(t4[1][2], t4[1][3], t4[2][0]);
        float md = fmax3(t4[2][1], t4[2][2], t4[2][3]);
        float me = fmax3(t4[3][0], t4[3][1], t4[3][2]);
        float tm = fmax3(fmax3(ma, mb, mc), fmax3(md, me, t4[3][3]), -3.0e38f);
        if (!__all(tm <= THR)) {
            // rare: reduce max across the 4 g-groups (same q-row c)
            float pm = tm;
            pm = fmaxf(pm, __shfl_xor(pm, 16));
            pm = fmaxf(pm, __shfl_xor(pm, 32));
            float dm = fmaxf(pm, 0.f);
            nm2 -= dm;
            float alpha = exp2f(-dm);
            for (int nt = 0; nt < 4; ++nt)
                for (int r = 0; r < 4; ++r) t4[nt][r] -= dm;
            for (int r = 0; r < 4; ++r) {
                float ar = __shfl(alpha, 4 * g + r);
                for (int nd = 0; nd < 4; ++nd) o[nd][r] *= ar;
                lacc[r] *= ar;
            }
        }

        // p = 2^t, pack to mfma16 A-fragments
        bf16x4 pf[4];
        for (int nt = 0; nt < 4; ++nt) {
            float p0 = exp2f(t4[nt][0]), p1 = exp2f(t4[nt][1]);
            float p2 = exp2f(t4[nt][2]), p3 = exp2f(t4[nt][3]);
            union { unsigned u[2]; bf16x4 v; } pk;
            pk.u[0] = packbf2(p0, p1);
            pk.u[1] = packbf2(p2, p3);
            pf[nt] = pk.v;
        }

        // O += P V ; l += P * ones (row-sum, consistent with bf16 numerator)
        for (int nd = 0; nd < 4; ++nd)
            for (int nt = 0; nt < 4; ++nt) {
                bf16x4 vf = *(const bf16x4*)&Vs[nd * 16 + c][nt * 16 + 4 * g];
                o[nd] = mfma16(pf[nt], vf, o[nd]);
            }
        for (int nt = 0; nt < 4; ++nt)
            lacc = mfma16(pf[nt], ones, lacc);
    }

    const int b = bh >> 3, h = bh & 7;
    for (int r = 0; r < 4; ++r) {
        float inv = 1.f / lacc[r];
        int m = b * 4096 + q0 + w * 16 + 4 * g + r;
        for (int nd = 0; nd < 4; ++nd) {
            int n = h * 64 + nd * 16 + c;
            Mo[(size_t)m * 512 + n] = f2bf(o[nd][r] * inv);
        }
    }
}

extern "C" void kernel_launch(void* const* d_in, const int* in_sizes, int n_in,
                              void* d_out, int out_size, void* d_ws, size_t ws_size,
                              hipStream_t stream) {
    const float* q  = (const float*)d_in[0];
    const float* Wq = (const float*)d_in[1];
    const float* bq = (const float*)d_in[2];
    const float* Wk = (const float*)d_in[3];
    const float* bk = (const float*)d_in[4];
    const float* Wv = (const float*)d_in[5];
    const float* bv = (const float*)d_in[6];
    const float* Wo = (const float*)d_in[7];
    const float* bo = (const float*)d_in[8];

    unsigned short* Qb = (unsigned short*)d_ws;            // 8 MB
    unsigned short* Kb = Qb + (size_t)16 * 4096 * 64;      // 8 MB
    unsigned short* Vt = Kb + (size_t)16 * 4096 * 64;      // 8 MB (V^T per head)
    unsigned short* Mg = Vt + (size_t)16 * 4096 * 64;      // merged bf16 [8192][512]

    dim3 gb(256);
    dim3 gqkv(64, 4, 3);
    gemm_qkv<<<gqkv, gb, 0, stream>>>(q, Wq, bq, Wk, bk, Wv, bv, Qb, Kb, Vt);

    dim3 ga(1024);
    attn64<<<ga, gb, 0, stream>>>(Qb, Kb, Vt, Mg);

    dim3 gg(64, 4);
    gemm_out<<<gg, gb, 0, stream>>>(Mg, Wo, bo, (float*)d_out);
}